// Round 1
// baseline (279.305 us; speedup 1.0000x reference)
//
#include <hip/hip_runtime.h>
#include <hip/hip_bf16.h>
#include <stdint.h>

#define NSEQ 128
#define SEQ  256
#define MSA  256
#define HD   32
#define PD   128

typedef short bf16x8 __attribute__((ext_vector_type(8)));
typedef float f32x4  __attribute__((ext_vector_type(4)));
typedef short s16x4  __attribute__((ext_vector_type(4)));

__device__ __forceinline__ short f2bf(float x) {
    union { float f; uint32_t u; } v; v.f = x;
    uint32_t r = v.u + 0x7FFFu + ((v.u >> 16) & 1u);   // RNE
    return (short)(r >> 16);
}

// ---------------- Kernel 1: LayerNorm (one wave per row) ----------------
__global__ __launch_bounds__(256) void k_ln(const float* __restrict__ msa,
                                            const float* __restrict__ nw,
                                            const float* __restrict__ nb,
                                            float* __restrict__ out) {
    int row = blockIdx.x * 4 + (threadIdx.x >> 6);   // 32768 rows
    int l   = threadIdx.x & 63;
    const float* x = msa + (size_t)row * MSA;
    float4 v = *(const float4*)(x + l * 4);
    float s = v.x + v.y + v.z + v.w;
    for (int o = 32; o > 0; o >>= 1) s += __shfl_xor(s, o, 64);
    float mu = s * (1.0f / 256.0f);
    float dx = v.x - mu, dy = v.y - mu, dz = v.z - mu, dw = v.w - mu;
    float sq = dx*dx + dy*dy + dz*dz + dw*dw;
    for (int o = 32; o > 0; o >>= 1) sq += __shfl_xor(sq, o, 64);
    float rs = rsqrtf(sq * (1.0f / 256.0f) + 1e-5f);
    float4 w = *(const float4*)(nw + l * 4);
    float4 b = *(const float4*)(nb + l * 4);
    float4 o4;
    o4.x = dx * rs * w.x + b.x;
    o4.y = dy * rs * w.y + b.y;
    o4.z = dz * rs * w.z + b.z;
    o4.w = dw * rs * w.w + b.w;
    *(float4*)(out + (size_t)row * MSA + l * 4) = o4;
}

// ---------------- Kernel 2: w3 [1024][128] f32 -> w3t bf16 [128][1024] ----------------
__global__ __launch_bounds__(256) void k_w3t(const float* __restrict__ w3,
                                             short* __restrict__ w3t) {
    int gid = blockIdx.x * 256 + threadIdx.x;        // 131072
    int p = gid >> 10, k = gid & 1023;
    w3t[gid] = f2bf(w3[k * PD + p]);
}

// ---------------- Kernel 3: projections (fp32 4x4 microkernel) ----------------
// block = (i, n-chunk); computes proj for 64 n x 64 cols (32 a via w2, 32 b via w1)
// writes pa/pb as bf16 [m = i*32+c][n]  (K(=n)-contiguous for MFMA fragments)
__global__ __launch_bounds__(256) void k_proj(const float* __restrict__ nrm,
                                              const float* __restrict__ w1,
                                              const float* __restrict__ b1,
                                              const float* __restrict__ w2,
                                              const float* __restrict__ b2,
                                              short* __restrict__ pa,
                                              short* __restrict__ pb) {
    __shared__ float nlds[64][132];
    __shared__ float wlds[64][132];
    int i  = blockIdx.x;         // seq position
    int nb = blockIdx.y;         // n chunk (0..1)
    int t  = threadIdx.x;
    int tr = t >> 4, tc = t & 15;
    float acc[4][4] = {};
    for (int dc = 0; dc < 2; ++dc) {
        __syncthreads();
        // stage normed: 64 rows x 128 f32 (rows = n, fixed i)
        for (int it = 0; it < 8; ++it) {
            int nn = it * 8 + (t >> 5);
            int c4 = t & 31;
            const float* src = nrm + ((size_t)(nb * 64 + nn) * SEQ + i) * MSA + dc * 128 + c4 * 4;
            *(float4*)&nlds[nn][c4 * 4] = *(const float4*)src;
        }
        // stage weights transposed: wlds[c][dd]
        for (int it = 0; it < 32; ++it) {
            int e  = it * 256 + t;
            int dd = e >> 6;
            int c  = e & 63;
            float wv = (c < 32) ? w2[(dc * 128 + dd) * HD + c]
                                : w1[(dc * 128 + dd) * HD + (c - 32)];
            wlds[c][dd] = wv;
        }
        __syncthreads();
        for (int d4 = 0; d4 < 32; ++d4) {
            float4 nv[4], wv[4];
            for (int rr = 0; rr < 4; ++rr) nv[rr] = *(float4*)&nlds[tr * 4 + rr][d4 * 4];
            for (int cc = 0; cc < 4; ++cc) wv[cc] = *(float4*)&wlds[tc * 4 + cc][d4 * 4];
            for (int rr = 0; rr < 4; ++rr)
                for (int cc = 0; cc < 4; ++cc)
                    acc[rr][cc] += nv[rr].x * wv[cc].x + nv[rr].y * wv[cc].y +
                                   nv[rr].z * wv[cc].z + nv[rr].w * wv[cc].w;
        }
    }
    // bias + transposed coalesced write (4 consecutive n per thread)
    for (int cc = 0; cc < 4; ++cc) {
        int c = tc * 4 + cc;
        float bias = (c < 32) ? b2[c] : b1[c - 32];
        s16x4 o;
        o[0] = f2bf(acc[0][cc] + bias);
        o[1] = f2bf(acc[1][cc] + bias);
        o[2] = f2bf(acc[2][cc] + bias);
        o[3] = f2bf(acc[3][cc] + bias);
        int cl = (c < 32) ? c : (c - 32);
        short* dst = (c < 32) ? pa : pb;
        size_t off = ((size_t)(i * HD + cl)) * NSEQ + nb * 64 + tr * 4;
        *(s16x4*)(dst + off) = o;
    }
}

// ---------------- Kernel 4: fused outer-product GEMM + w3 GEMM ----------------
// grid 64x64 (4 i x 4 j per block). GEMM1: 128x128x128 bf16 MFMA.
// Repack acc -> A2 [16 pairs][1024] bf16 in LDS (reuses As/Bs), GEMM2: 16x128x1024.
__global__ __launch_bounds__(256) void k_outer(const short* __restrict__ pa,
                                               const short* __restrict__ pb,
                                               const short* __restrict__ w3t,
                                               const float* __restrict__ b3,
                                               float* __restrict__ out) {
    __shared__ short smem[32768];                 // 64 KB: As 32KB | Bs 32KB, later A2
    int t = threadIdx.x, l = t & 63, wid = t >> 6;
    // XCD-bijective swizzle (4096 % 8 == 0)
    int lin = blockIdx.y * 64 + blockIdx.x;
    int swz = (lin & 7) * 512 + (lin >> 3);
    int bi = swz >> 6, bj = swz & 63;
    int m0 = bi * 128, n0 = bj * 128;
    short* As = smem;
    short* Bs = smem + 16384;
    // ---- stage A/B tiles (XOR-swizzled 16B chunks: slot = kc ^ (row&7)) ----
    for (int it = 0; it < 8; ++it) {
        int row = it * 16 + (t >> 4);
        int kc  = t & 15;
        int skc = kc ^ (row & 7);
        *(bf16x8*)(As + row * 128 + skc * 8) = *(const bf16x8*)(pa + (size_t)(m0 + row) * 128 + kc * 8);
        *(bf16x8*)(Bs + row * 128 + skc * 8) = *(const bf16x8*)(pb + (size_t)(n0 + row) * 128 + kc * 8);
    }
    __syncthreads();
    // ---- GEMM1: wave (wm,wn) owns 64x64, 4x4 fragments of 16x16 ----
    int wm = wid >> 1, wn = wid & 1;
    int lr = l & 15, lk = l >> 4;
    f32x4 acc[4][4] = {};
    for (int ks = 0; ks < 4; ++ks) {
        bf16x8 af[4], bff[4];
        for (int mf = 0; mf < 4; ++mf) {
            int row = wm * 64 + mf * 16 + lr;
            int kc  = ks * 4 + lk;
            af[mf] = *(bf16x8*)(As + row * 128 + ((kc ^ (row & 7)) * 8));
        }
        for (int nf = 0; nf < 4; ++nf) {
            int row = wn * 64 + nf * 16 + lr;
            int kc  = ks * 4 + lk;
            bff[nf] = *(bf16x8*)(Bs + row * 128 + ((kc ^ (row & 7)) * 8));
        }
        for (int mf = 0; mf < 4; ++mf)
            for (int nf = 0; nf < 4; ++nf)
                acc[mf][nf] = __builtin_amdgcn_mfma_f32_16x16x32_bf16(af[mf], bff[nf], acc[mf][nf], 0, 0, 0);
    }
    __syncthreads();
    // ---- repack acc -> A2 [16][1032] bf16 (pair = ii*4+jj, kk = a*32+b), /= n_seq ----
    const float inv_n = 1.0f / 128.0f;
    short* A2 = smem;
    for (int mf = 0; mf < 4; ++mf)
        for (int nf = 0; nf < 4; ++nf)
            for (int r = 0; r < 4; ++r) {
                int m = wm * 64 + mf * 16 + lk * 4 + r;   // (ii, a)
                int n = wn * 64 + nf * 16 + lr;           // (jj, b)
                int pair = (m >> 5) * 4 + (n >> 5);
                int kk   = (m & 31) * 32 + (n & 31);
                A2[pair * 1032 + kk] = f2bf(acc[mf][nf][r] * inv_n);
            }
    __syncthreads();
    // ---- GEMM2: M=16 pairs, K=1024, N=128; wave wid owns p-range [wid*32, wid*32+32) ----
    f32x4 acc2[2] = {};
    for (int ks = 0; ks < 32; ++ks) {
        bf16x8 a2 = *(bf16x8*)(A2 + lr * 1032 + ks * 32 + lk * 8);
        for (int nf = 0; nf < 2; ++nf) {
            int p = wid * 32 + nf * 16 + lr;
            bf16x8 b2 = *(const bf16x8*)(w3t + (size_t)p * 1024 + ks * 32 + lk * 8);
            acc2[nf] = __builtin_amdgcn_mfma_f32_16x16x32_bf16(a2, b2, acc2[nf], 0, 0, 0);
        }
    }
    // ---- epilogue: out[i][j][p] = acc2 + b3[p] ----
    for (int nf = 0; nf < 2; ++nf) {
        int p = wid * 32 + nf * 16 + lr;
        float bias = b3[p];
        for (int r = 0; r < 4; ++r) {
            int pair = lk * 4 + r;
            int i = bi * 4 + (pair >> 2);
            int j = bj * 4 + (pair & 3);
            out[((size_t)i * SEQ + j) * PD + p] = acc2[nf][r] + bias;
        }
    }
}

extern "C" void kernel_launch(void* const* d_in, const int* in_sizes, int n_in,
                              void* d_out, int out_size, void* d_ws, size_t ws_size,
                              hipStream_t stream) {
    const float* msa = (const float*)d_in[0];
    const float* nw  = (const float*)d_in[1];
    const float* nbv = (const float*)d_in[2];
    const float* w1  = (const float*)d_in[3];
    const float* b1  = (const float*)d_in[4];
    const float* w2  = (const float*)d_in[5];
    const float* b2  = (const float*)d_in[6];
    const float* w3  = (const float*)d_in[7];
    const float* b3  = (const float*)d_in[8];
    float* out = (float*)d_out;

    char* ws = (char*)d_ws;
    float* nrm = (float*)ws;                          // 32 MB  (32768*256 f32)
    short* pa  = (short*)(ws + (32u << 20));          // 2 MB   (8192*128 bf16)
    short* pb  = (short*)(ws + (34u << 20));          // 2 MB
    short* w3t = (short*)(ws + (36u << 20));          // 256 KB (128*1024 bf16)

    k_ln  <<<8192, 256, 0, stream>>>(msa, nw, nbv, nrm);
    k_w3t <<<512, 256, 0, stream>>>(w3, w3t);
    k_proj<<<dim3(256, 2), 256, 0, stream>>>(nrm, w1, b1, w2, b2, pa, pb);
    k_outer<<<dim3(64, 64), 256, 0, stream>>>(pa, pb, w3t, b3, out);
}

// Round 2
// 144.422 us; speedup vs baseline: 1.9339x; 1.9339x over previous
//
#include <hip/hip_runtime.h>
#include <hip/hip_bf16.h>
#include <stdint.h>

#define SEQ  256
#define PD   128

typedef short bf16x8 __attribute__((ext_vector_type(8)));
typedef float f32x4  __attribute__((ext_vector_type(4)));
typedef float f32x16 __attribute__((ext_vector_type(16)));
typedef short s16x4  __attribute__((ext_vector_type(4)));

__device__ __forceinline__ short f2bf(float x) {
    union { float f; uint32_t u; } v; v.f = x;
    uint32_t r = v.u + 0x7FFFu + ((v.u >> 16) & 1u);   // RNE
    return (short)(r >> 16);
}

__device__ __forceinline__ void gld16(const void* g, void* l) {
    __builtin_amdgcn_global_load_lds(
        (const __attribute__((address_space(1))) void*)g,
        (__attribute__((address_space(3))) void*)l, 16, 0, 0);
}

// ============ k_prep: pack weights ============
// w12t: [64 cols][256 k] bf16, 16B-chunk pre-swizzled: slot (col,c') = logical (col, c'^(col&7))
// w3p : B-fragment order for 32x32x16: chunk g=(pg*64+ks)*64+l holds w3[ks*16+(l>>5)*8+e][pg*32+(l&31)]
__global__ __launch_bounds__(256) void k_prep(const float* __restrict__ w1,
                                              const float* __restrict__ w2,
                                              const float* __restrict__ w3,
                                              short* __restrict__ w12t,
                                              short* __restrict__ w3p) {
    int id = blockIdx.x * 256 + threadIdx.x;           // 18432 total
    if (id < 2048) {
        int col = id >> 5, cp = id & 31;
        int c = cp ^ (col & 7);
        bf16x8 o;
        #pragma unroll
        for (int e = 0; e < 8; ++e) {
            int k = c * 8 + e;
            float v = (col < 32) ? w2[k * 32 + col] : w1[k * 32 + (col - 32)];
            o[e] = f2bf(v);
        }
        *(bf16x8*)(w12t + id * 8) = o;
    } else {
        int id2 = id - 2048;                           // 0..16383
        int pg = id2 >> 12, ks = (id2 >> 6) & 63, l2 = id2 & 63;
        bf16x8 o;
        #pragma unroll
        for (int e = 0; e < 8; ++e) {
            int k = ks * 16 + (l2 >> 5) * 8 + e;
            int p = pg * 32 + (l2 & 31);
            o[e] = f2bf(w3[k * 128 + p]);
        }
        *(bf16x8*)(w3p + id2 * 8) = o;
    }
}

// ============ k_fused: LayerNorm + both projections ============
// grid (i=256, nb=2), 256 thr. LDS: W [0,32KB) staged from w12t; As(normed bf16) [32KB,64KB)
__global__ __launch_bounds__(256) void k_fused(const float* __restrict__ msa,
                                               const float* __restrict__ nw,
                                               const float* __restrict__ nb_,
                                               const float* __restrict__ b1,
                                               const float* __restrict__ b2,
                                               const short* __restrict__ w12t,
                                               short* __restrict__ pa,
                                               short* __restrict__ pb) {
    __shared__ short smem[32768];                      // 64 KB
    int i = blockIdx.x, nbk = blockIdx.y;
    int t = threadIdx.x, l = t & 63, w = t >> 6;

    // stage W (32KB) async
    #pragma unroll
    for (int it = 0; it < 8; ++it) {
        int ci = it * 256 + t;
        gld16(w12t + (size_t)ci * 8, smem + (it * 256 + (t & ~63)) * 8);
    }
    // load 16 msa rows (this wave's n-rows), LN in registers
    float4 x[16];
    const float* basep = msa + ((size_t)(nbk * 64 + w * 16) * SEQ + i) * 256 + l * 4;
    #pragma unroll
    for (int j = 0; j < 16; ++j)
        x[j] = *(const float4*)(basep + (size_t)j * SEQ * 256);
    float4 wv = *(const float4*)(nw + l * 4);
    float4 bv = *(const float4*)(nb_ + l * 4);
    #pragma unroll
    for (int j = 0; j < 16; ++j) {
        float s = x[j].x + x[j].y + x[j].z + x[j].w;
        #pragma unroll
        for (int o = 32; o > 0; o >>= 1) s += __shfl_xor(s, o, 64);
        float mu = s * (1.0f / 256.0f);
        float dx = x[j].x - mu, dy = x[j].y - mu, dz = x[j].z - mu, dw = x[j].w - mu;
        float sq = dx * dx + dy * dy + dz * dz + dw * dw;
        #pragma unroll
        for (int o = 32; o > 0; o >>= 1) sq += __shfl_xor(sq, o, 64);
        float rs = rsqrtf(sq * (1.0f / 256.0f) + 1e-5f);
        s16x4 o4;
        o4[0] = f2bf(dx * rs * wv.x + bv.x);
        o4[1] = f2bf(dy * rs * wv.y + bv.y);
        o4[2] = f2bf(dz * rs * wv.z + bv.z);
        o4[3] = f2bf(dw * rs * wv.w + bv.w);
        int row = w * 16 + j;
        *(s16x4*)((char*)smem + 32768 + row * 512 + (((l >> 1) ^ (row & 7)) * 16) + (l & 1) * 8) = o4;
    }
    __syncthreads();
    // MFMA: D[c_out 64][n 16/wave] = W (A-op) x As (B-op), K=256
    int lr = l & 15, lk = l >> 4;
    f32x4 acc[4] = {};
    #pragma unroll
    for (int ks = 0; ks < 8; ++ks) {
        int c = ks * 4 + lk;
        int xr = w * 16 + lr;
        bf16x8 xf = *(bf16x8*)((char*)smem + 32768 + xr * 512 + ((c ^ (xr & 7)) * 16));
        #pragma unroll
        for (int af = 0; af < 4; ++af) {
            int rw = af * 16 + lr;
            bf16x8 wf = *(bf16x8*)((char*)smem + rw * 512 + ((c ^ (rw & 7)) * 16));
            acc[af] = __builtin_amdgcn_mfma_f32_16x16x32_bf16(wf, xf, acc[af], 0, 0, 0);
        }
    }
    // epilogue: lane holds col n = w*16+lr, rows c_out = af*16+lk*4+r
    int nglob = nbk * 64 + w * 16 + lr;
    #pragma unroll
    for (int af = 0; af < 4; ++af) {
        #pragma unroll
        for (int r = 0; r < 4; ++r) {
            int cc = af * 16 + lk * 4 + r;
            float bias = (cc < 32) ? b2[cc] : b1[cc - 32];
            short v = f2bf(acc[af][r] + bias);
            if (cc < 32) pa[(size_t)(i * 32 + cc) * 128 + nglob] = v;
            else         pb[(size_t)(i * 32 + (cc - 32)) * 128 + nglob] = v;
        }
    }
}

// ============ k_outer: 256x256 ij-tile, fused GEMM1 + GEMM2 ============
// 1024 thr (16 waves), LDS 128KB. Layout per 64KB half h (K-half):
//   As_h [256 rows][8 chunks16B swz c^=row&7] | Bs_h (+32KB). Later A2 half h:
//   [64 pairs][512 k] with chunk q' = q ^ (pair&7) ^ (((klocal>>6)&3)<<1)
__global__ __launch_bounds__(1024) void k_outer(const short* __restrict__ pa,
                                                const short* __restrict__ pb,
                                                const short* __restrict__ w3p,
                                                const float* __restrict__ b3,
                                                float* __restrict__ out) {
    __shared__ short smem[65536];                      // 128 KB
    int t = threadIdx.x, l = t & 63, w = t >> 6;
    int lin = blockIdx.x;                              // 1024 blocks, XCD-bijective swizzle
    int swz = (lin & 7) * 128 + (lin >> 3);
    int bi = swz >> 5, bj = swz & 31;

    // ---- stage As/Bs (128KB) with source-side pre-swizzle ----
    const short* srcA = pa + (size_t)bi * 256 * 128;
    const short* srcB = pb + (size_t)bj * 256 * 128;
    #pragma unroll
    for (int it = 0; it < 8; ++it) {
        int ci = it * 1024 + t;
        int half = ci >> 12, rem = ci & 4095;
        int buf = rem >> 11, s = rem & 2047;
        int row = s >> 3, cl = s & 7;
        int gch = (cl ^ (row & 7)) + 8 * half;
        const short* g = (buf ? srcB : srcA) + row * 128 + gch * 8;
        gld16(g, smem + (it * 1024 + (t & ~63)) * 8);
    }
    __syncthreads();

    // ---- GEMM1: D[n][m] via mfma(pbfrag, pafrag). wave tile 64n x 64m ----
    int wm = w & 3, wn = w >> 2;
    int lr = l & 15, lk = l >> 4;
    f32x4 acc1[4][4] = {};                             // [nf][mf]
    #pragma unroll
    for (int ks = 0; ks < 4; ++ks) {
        int c = ks * 4 + lk, half = c >> 3, cl = c & 7;
        bf16x8 af[4];
        #pragma unroll
        for (int mf = 0; mf < 4; ++mf) {
            int row = wm * 64 + mf * 16 + lr;
            af[mf] = *(bf16x8*)((char*)smem + half * 65536 + row * 128 + ((cl ^ (row & 7)) * 16));
        }
        #pragma unroll
        for (int nf = 0; nf < 4; ++nf) {
            int row = wn * 64 + nf * 16 + lr;
            bf16x8 bf = *(bf16x8*)((char*)smem + half * 65536 + 32768 + row * 128 + ((cl ^ (row & 7)) * 16));
            #pragma unroll
            for (int mf = 0; mf < 4; ++mf)
                acc1[nf][mf] = __builtin_amdgcn_mfma_f32_16x16x32_bf16(bf, af[mf], acc1[nf][mf], 0, 0, 0);
        }
    }
    __syncthreads();

    // ---- repack: A2[pair][k=a*32+b] bf16, vector 8B writes (b-contiguous via swapped mfma) ----
    const float inv_n = 1.0f / 128.0f;
    #pragma unroll
    for (int nf = 0; nf < 4; ++nf) {
        #pragma unroll
        for (int mf = 0; mf < 4; ++mf) {
            int pair = (wm * 2 + (mf >> 1)) * 8 + (wn * 2 + (nf >> 1));
            int b = (nf & 1) * 16 + lk * 4;            // + r
            int q = lr * 4 + 2 * (nf & 1) + (lk >> 1); // (a&15)*4 + b>>3, a&15 = lr
            int qp = q ^ (pair & 7) ^ (((lr >> 1) & 3) << 1);
            s16x4 o;
            #pragma unroll
            for (int r = 0; r < 4; ++r) o[r] = f2bf(acc1[nf][mf][r] * inv_n);
            *(s16x4*)((char*)smem + (mf & 1) * 65536 + pair * 1024 + qp * 16 + (b & 7) * 2) = o;
        }
    }
    __syncthreads();

    // ---- GEMM2: M=64 pairs, N=128 p, K=1024. 32x32x16 MFMA, waves 0..7 ----
    // wave: pg = w>>1 (p-group of 32), kh = w&1 (K-half). B-dup = 1.
    f32x16 acc2[2] = {};
    int pg = w >> 1, kh = w & 1;
    if (w < 8) {
        #pragma unroll
        for (int ksi = 0; ksi < 32; ++ksi) {
            int ksg = kh * 32 + ksi;
            bf16x8 b2f = *(const bf16x8*)(w3p + ((size_t)(pg * 64 + ksg) * 64 + l) * 8);
            int q = (ksg & 31) * 2 + (l >> 5);
            int sa = (((ksg & 31) >> 2) & 3) << 1;
            #pragma unroll
            for (int mq = 0; mq < 2; ++mq) {
                int prow = mq * 32 + (l & 31);
                int qp = q ^ (prow & 7) ^ sa;
                bf16x8 a2 = *(bf16x8*)((char*)smem + kh * 65536 + prow * 1024 + qp * 16);
                acc2[mq] = __builtin_amdgcn_mfma_f32_32x32x16_bf16(a2, b2f, acc2[mq], 0, 0, 0);
            }
        }
    }
    __syncthreads();
    // ---- 2-way K-reduction via LDS scratch (32KB) ----
    float* scratch = (float*)smem;
    if (w < 8 && kh == 1) {
        #pragma unroll
        for (int mq = 0; mq < 2; ++mq)
            #pragma unroll
            for (int r = 0; r < 16; ++r)
                scratch[((mq * 4 + pg) * 16 + r) * 64 + l] = acc2[mq][r];
    }
    __syncthreads();
    if (w < 8 && kh == 0) {
        float bias = b3[pg * 32 + (l & 31)];
        int p = pg * 32 + (l & 31);
        #pragma unroll
        for (int mq = 0; mq < 2; ++mq) {
            #pragma unroll
            for (int r = 0; r < 16; ++r) {
                float v = acc2[mq][r] + scratch[((mq * 4 + pg) * 16 + r) * 64 + l];
                int pair = mq * 32 + (r & 3) + 8 * (r >> 2) + 4 * (l >> 5);
                int oi = bi * 8 + (pair >> 3), oj = bj * 8 + (pair & 7);
                out[((size_t)(oi * 256 + oj)) * 128 + p] = v + bias;
            }
        }
    }
}

extern "C" void kernel_launch(void* const* d_in, const int* in_sizes, int n_in,
                              void* d_out, int out_size, void* d_ws, size_t ws_size,
                              hipStream_t stream) {
    const float* msa = (const float*)d_in[0];
    const float* nw  = (const float*)d_in[1];
    const float* nbv = (const float*)d_in[2];
    const float* w1  = (const float*)d_in[3];
    const float* b1  = (const float*)d_in[4];
    const float* w2  = (const float*)d_in[5];
    const float* b2  = (const float*)d_in[6];
    const float* w3  = (const float*)d_in[7];
    const float* b3  = (const float*)d_in[8];
    float* out = (float*)d_out;

    char* ws = (char*)d_ws;
    short* pa   = (short*)ws;                          // 2 MB   (8192 x 128 bf16)
    short* pb   = (short*)(ws + (2u << 20));           // 2 MB
    short* w3p  = (short*)(ws + (4u << 20));           // 256 KB
    short* w12t = (short*)(ws + (4u << 20) + (256u << 10)); // 32 KB

    k_prep <<<72, 256, 0, stream>>>(w1, w2, w3, w12t, w3p);
    k_fused<<<dim3(256, 2), 256, 0, stream>>>(msa, nw, nbv, b1, b2, w12t, pa, pb);
    k_outer<<<1024, 1024, 0, stream>>>(pa, pb, w3p, b3, out);
}